// Round 1
// baseline (1061.012 us; speedup 1.0000x reference)
//
#include <hip/hip_runtime.h>

// Problem constants (reference: B=1024, P=128, KPASS=1)
#define PP   128        // P
#define H    127        // P-1 (hidden dim / MLP output dim)
#define NS   508        // 4*H : four per-k partial vectors P1,P2,P3,P4
#define NB   1024       // batch
#define BCH  256        // batch chunk (4 chunks) to bound workspace at ~100MB

// Mathematical reduction of the reference (see analysis):
//   out[b,r,c] = Theta[b,r,c]                                   if r==c
//              = 129*t12n[b,max(r,c),min(r,c)] - 128*Theta[b,r,c] otherwise
// where t12n[b,col,:] = relu(feats(b,col) @ W1 + b1) @ W2 + b2 and feats is the
// compacted-submatrix feature vector built from the ORIGINAL Theta only.
// Layer-1 is evaluated via quadrant prefix decomposition:
//   z1[b,col,o] = b1[o] + sum_{k<col} P1[b,k,o] - sum_{1<=k<=col} P2[b,k,o]
//               + sum_{k>col} P3[b,k,o] + P4[b,col,o]
// with P{1..4}[b,k,:] = sum_c Theta[b,k,c] * WP{1..4}[k,c,:]  (Theta is symmetric).

// ---------------- Kernel A: build combined masked weights WP ----------------
// WP[(k*128 + c)*508 + v*127 + o], v in {0:P1, 1:P2, 2:P3, 3:P4}
// V(i,j,o) = W1[(i*127+j)*127 + o]; Wt(i,o) = W1[(16129+i)*127+o]; wd(o)=W1[16256*127+o]
__global__ __launch_bounds__(128) void build_wp(const float* __restrict__ W1,
                                                float* __restrict__ WP) {
  int bid = blockIdx.x;            // 128*128 blocks
  int k = bid >> 7, c = bid & 127;
  int t = threadIdx.x;
  for (int n = t; n < NS; n += 128) {
    int v = n / H;
    int o = n - v * H;             // 0..126
    float val = 0.f;
    if (v == 0) {                  // P1 = inc00 + u + u'   (k<=126; P1[127]=0)
      if (k <= 126) {
        if (c < k)       val = W1[(k*H + c)*H + o]     + W1[(c*H + k)*H + o];
        else if (c == k) val = W1[(k*H + k)*H + o];
        else             val = W1[(k*H + (c-1))*H + o] + W1[((c-1)*H + k)*H + o];
      }
    } else if (v == 1) {           // P2 = v + v'           (k>=1; P2[0]=0)
      if (k >= 1 && c < k) val = W1[(c*H + (k-1))*H + o] + W1[((k-1)*H + c)*H + o];
    } else if (v == 2) {           // P3 = inc11            (k>=1; P3[0]=0)
      if (k >= 1) {
        if (c > k)       val = W1[((k-1)*H + (c-1))*H + o] + W1[((c-1)*H + (k-1))*H + o];
        else if (c == k) val = W1[((k-1)*H + (k-1))*H + o];
      }
    } else {                       // P4 = t12-part + diag term
      if (c < k)       val = W1[(16129 + c)*H + o];
      else if (c == k) val = W1[16256*H + o];
      else             val = W1[(16129 + (c-1))*H + o];
    }
    WP[(k*PP + c)*NS + n] = val;
  }
}

// ---------------- Kernel B: P[bl][k][n] = sum_c Th[b,k,c]*WP[k][c][n] --------
// Grid: x = (k*4 + bt)*4 + nt ; 128 k * 4 btiles(64) * 4 ntiles(128) = 2048 WGs
__global__ __launch_bounds__(256) void pgemm(const float* __restrict__ Th,
                                             const float* __restrict__ WP,
                                             float* __restrict__ P, int bbase) {
  __shared__ float Al[64 * 65];    // [b-row][c], +1 pad vs bank aliasing
  __shared__ float Bl[64 * 128];   // [c][n]
  int x  = blockIdx.x;
  int nt = x & 3, bt = (x >> 2) & 3, k = x >> 4;
  int n0 = nt * 128;
  int b0l = bt * 64;               // chunk-local batch base
  int tid = threadIdx.x;
  int tn = tid & 15, tm = tid >> 4;
  float acc[4][8];
  #pragma unroll
  for (int i = 0; i < 4; ++i)
    #pragma unroll
    for (int j = 0; j < 8; ++j) acc[i][j] = 0.f;

  for (int kc = 0; kc < 128; kc += 64) {
    for (int idx = tid; idx < 64 * 64; idx += 256) {       // A: coalesced rows
      int rb = idx >> 6, cc = idx & 63;
      Al[rb * 65 + cc] = Th[((bbase + b0l + rb) * PP + k) * PP + kc + cc];
    }
    for (int idx = tid; idx < 64 * 128; idx += 256) {      // B: coalesced rows
      int cc = idx >> 7, nn = idx & 127;
      int n = n0 + nn;
      Bl[cc * 128 + nn] = (n < NS) ? WP[(k * PP + kc + cc) * NS + n] : 0.f;
    }
    __syncthreads();
    #pragma unroll 8
    for (int kk = 0; kk < 64; ++kk) {
      float a0 = Al[(tm * 4 + 0) * 65 + kk];
      float a1 = Al[(tm * 4 + 1) * 65 + kk];
      float a2 = Al[(tm * 4 + 2) * 65 + kk];
      float a3 = Al[(tm * 4 + 3) * 65 + kk];
      const float4 bx = *(const float4*)&Bl[kk * 128 + tn * 8];
      const float4 by = *(const float4*)&Bl[kk * 128 + tn * 8 + 4];
      float bv[8] = {bx.x, bx.y, bx.z, bx.w, by.x, by.y, by.z, by.w};
      #pragma unroll
      for (int j = 0; j < 8; ++j) {
        acc[0][j] += a0 * bv[j];
        acc[1][j] += a1 * bv[j];
        acc[2][j] += a2 * bv[j];
        acc[3][j] += a3 * bv[j];
      }
    }
    __syncthreads();
  }
  #pragma unroll
  for (int i = 0; i < 4; ++i) {
    int bl = b0l + tm * 4 + i;
    int base = (bl * PP + k) * NS;
    #pragma unroll
    for (int j = 0; j < 8; ++j) {
      int n = n0 + tn * 8 + j;
      if (n < NS) P[base + n] = acc[i][j];
    }
  }
}

// ---------------- Kernel C: prefix scans over k + ReLU ----------------------
// z1[col] = b1 + sum_{k<col}P1 - sum_{1<=k<=col}P2 + sum_{k>col}P3 + P4[col]
// relu(z1) overwrites the P1 slot (read-before-write order is safe per-column).
__global__ __launch_bounds__(128) void scan_c(float* __restrict__ P,
                                              const float* __restrict__ b1) {
  __shared__ float zl[PP * H];     // 63.5 KiB
  int bl = blockIdx.x;
  int o  = threadIdx.x;
  float* Pb = P + (size_t)bl * PP * NS;
  if (o < H) {
    float F = b1[o];
    for (int col = 0; col < PP; ++col) {
      if (col > 0) F += Pb[(col - 1) * NS + o];   // + P1[col-1]
      F -= Pb[col * NS + H + o];                  // - P2[col]  (P2[0]==0)
      zl[col * H + o] = F + Pb[col * NS + 3 * H + o];  // + P4[col]
    }
  }
  __syncthreads();
  if (o < H) {
    float Bt = 0.f;
    for (int col = PP - 1; col >= 0; --col) {
      float z = zl[col * H + o] + Bt;
      Pb[col * NS + o] = fmaxf(z, 0.f);           // A = relu(z1) into P1 slot
      Bt += Pb[col * NS + 2 * H + o];             // accumulate P3 (suffix)
    }
  }
}

// ---------------- Kernel D: t12n = A @ W2 + b2, fused output scatter --------
// One workgroup per batch element: full 128x127 result staged in LDS, then the
// whole 128x128 output tile (incl. diagonal) written coalesced.
__global__ __launch_bounds__(256) void gemm2(const float* __restrict__ P,
                                             const float* __restrict__ W2,
                                             const float* __restrict__ b2,
                                             const float* __restrict__ Th,
                                             float* __restrict__ out, int bbase) {
  __shared__ float smem[PP * H];   // 63.5 KiB; phase1: Al[128*33]+W2l[32*128]=8320f
  float* Al  = smem;               // [128][33]
  float* W2l = smem + 128 * 33;    // [32][128]
  int bl = blockIdx.x;
  int b  = bbase + bl;
  int tid = threadIdx.x;
  int tn = tid & 15, tm = tid >> 4;
  const float* Ab = P + (size_t)bl * PP * NS;    // relu(z1), row stride NS
  float acc[8][8];
  #pragma unroll
  for (int i = 0; i < 8; ++i)
    #pragma unroll
    for (int j = 0; j < 8; ++j) {
      int o = tn * 8 + j;
      acc[i][j] = (o < H) ? b2[o] : 0.f;
    }
  for (int kc = 0; kc < H; kc += 32) {
    for (int idx = tid; idx < 128 * 32; idx += 256) {
      int col = idx >> 5, jj = idx & 31;
      Al[col * 33 + jj] = (kc + jj < H) ? Ab[col * NS + kc + jj] : 0.f;
    }
    for (int idx = tid; idx < 32 * 128; idx += 256) {
      int jj = idx >> 7, o = idx & 127;
      W2l[jj * 128 + o] = (kc + jj < H && o < H) ? W2[(kc + jj) * H + o] : 0.f;
    }
    __syncthreads();
    #pragma unroll 4
    for (int kk = 0; kk < 32; ++kk) {
      float a_[8];
      #pragma unroll
      for (int i = 0; i < 8; ++i) a_[i] = Al[(tm * 8 + i) * 33 + kk];
      const float4 bx = *(const float4*)&W2l[kk * 128 + tn * 8];
      const float4 by = *(const float4*)&W2l[kk * 128 + tn * 8 + 4];
      float bv[8] = {bx.x, bx.y, bx.z, bx.w, by.x, by.y, by.z, by.w};
      #pragma unroll
      for (int i = 0; i < 8; ++i)
        #pragma unroll
        for (int j = 0; j < 8; ++j) acc[i][j] += a_[i] * bv[j];
    }
    __syncthreads();
  }
  // stage t12n into LDS: smem[col*H + o]
  #pragma unroll
  for (int i = 0; i < 8; ++i) {
    int col = tm * 8 + i;
    #pragma unroll
    for (int j = 0; j < 8; ++j) {
      int o = tn * 8 + j;
      if (o < H) smem[col * H + o] = acc[i][j];
    }
  }
  __syncthreads();
  const float* Tb = Th + (size_t)b * PP * PP;
  float* ob = out + (size_t)b * PP * PP;
  for (int it = 0; it < 64; ++it) {
    int idx = tid + 256 * it;      // covers 128*128
    int r = idx >> 7, c = idx & 127;
    float th = Tb[idx];
    float val;
    if (r == c) {
      val = th;
    } else {
      int M = r > c ? r : c, m = r > c ? c : r;
      val = 129.f * smem[M * H + m] - 128.f * th;   // stride-H reads: gcd(127,32)=1, conflict-free
    }
    ob[idx] = val;
  }
}

extern "C" void kernel_launch(void* const* d_in, const int* in_sizes, int n_in,
                              void* d_out, int out_size, void* d_ws, size_t ws_size,
                              hipStream_t stream) {
  const float* Th = (const float*)d_in[0];
  const float* W1 = (const float*)d_in[1];
  const float* b1 = (const float*)d_in[2];
  const float* W2 = (const float*)d_in[3];
  const float* b2 = (const float*)d_in[4];
  // d_in[5..8] (D1,d1,D2,d2) provably do not affect the returned Theta.
  float* out = (float*)d_out;

  float* WP = (float*)d_ws;                        // 128*128*508 f32 = 33.3 MB
  float* Pb = WP + (size_t)PP * PP * NS;           // 256*128*508 f32 = 66.6 MB

  build_wp<<<dim3(128 * 128), dim3(128), 0, stream>>>(W1, WP);
  for (int ch = 0; ch < 4; ++ch) {
    int bb = ch * BCH;
    pgemm<<<dim3(2048), dim3(256), 0, stream>>>(Th, WP, Pb, bb);
    scan_c<<<dim3(BCH), dim3(128), 0, stream>>>(Pb, b1);
    gemm2<<<dim3(BCH), dim3(256), 0, stream>>>(Pb, W2, b2, Th, out, bb);
  }
}

// Round 3
// 861.651 us; speedup vs baseline: 1.2314x; 1.2314x over previous
//
#include <hip/hip_runtime.h>

// Problem constants (reference: B=1024, P=128, KPASS=1)
#define PP   128        // P
#define H    127        // P-1 (hidden dim / MLP output dim)
#define NS   508        // 4*H : four per-k partial vectors P1,P2,P3,P4
#define NB   1024       // batch

// Mathematical reduction of the reference:
//   out[b,r,c] = Theta[b,r,c]                                     if r==c
//              = 129*t12n[b,max(r,c),min(r,c)] - 128*Theta[b,r,c] otherwise
// t12n[b,col,:] = relu(feats(b,col) @ W1 + b1) @ W2 + b2, feats built from the
// ORIGINAL Theta only. Layer-1 via quadrant prefix decomposition:
//   z1[b,col,o] = b1[o] + sum_{k<col} P1[b,k,o] - sum_{1<=k<=col} P2[b,k,o]
//               + sum_{k>col} P3[b,k,o] + P4[b,col,o]
// with P{1..4}[b,k,:] = sum_c Theta[b,k,c] * WP{1..4}[k,c,:].

// ---------------- Kernel A: build combined masked weights WP ----------------
__global__ __launch_bounds__(128) void build_wp(const float* __restrict__ W1,
                                                float* __restrict__ WP) {
  int bid = blockIdx.x;            // 128*128 blocks
  int k = bid >> 7, c = bid & 127;
  int t = threadIdx.x;
  for (int n = t; n < NS; n += 128) {
    int v = n / H;
    int o = n - v * H;             // 0..126
    float val = 0.f;
    if (v == 0) {                  // P1 = inc00 + u + u'   (P1[127]=0)
      if (k <= 126) {
        if (c < k)       val = W1[(k*H + c)*H + o]     + W1[(c*H + k)*H + o];
        else if (c == k) val = W1[(k*H + k)*H + o];
        else             val = W1[(k*H + (c-1))*H + o] + W1[((c-1)*H + k)*H + o];
      }
    } else if (v == 1) {           // P2 = v + v'           (P2[0]=0)
      if (k >= 1 && c < k) val = W1[(c*H + (k-1))*H + o] + W1[((k-1)*H + c)*H + o];
    } else if (v == 2) {           // P3 = inc11            (P3[0]=0)
      if (k >= 1) {
        if (c > k)       val = W1[((k-1)*H + (c-1))*H + o] + W1[((c-1)*H + (k-1))*H + o];
        else if (c == k) val = W1[((k-1)*H + (k-1))*H + o];
      }
    } else {                       // P4 = t12-part + diag term
      if (c < k)       val = W1[(16129 + c)*H + o];
      else if (c == k) val = W1[16256*H + o];
      else             val = W1[(16129 + (c-1))*H + o];
    }
    WP[(k*PP + c)*NS + n] = val;
  }
}

// ---------------- Kernel B: P[bl][k][n] = sum_c Th[b,k,c]*WP[k][c][n] --------
// grid(4 ntiles, BC/128 btiles, 128 k); 256 thr; 8x8/thread; A transposed in LDS
// so both operands are ds_read_b128: 4 b128 (48 LDS cyc) per 64 FMA (was 47/32).
__global__ __launch_bounds__(256) void pgemm(const float* __restrict__ Th,
                                             const float* __restrict__ WP,
                                             float* __restrict__ P, int bbase) {
  __shared__ float As[32][128];    // [cc][row]  (transposed A)
  __shared__ float Bs[32][128];    // [cc][nn]
  int nt = blockIdx.x, k = blockIdx.z;
  int b0 = bbase + blockIdx.y * 128;   // global batch base of this tile
  int n0 = nt * 128;
  int tid = threadIdx.x;
  int tx = tid & 15, ty = tid >> 4;
  float acc[8][8];
  #pragma unroll
  for (int i = 0; i < 8; ++i)
    #pragma unroll
    for (int j = 0; j < 8; ++j) acc[i][j] = 0.f;

  for (int kc = 0; kc < 128; kc += 32) {
    // stage A transposed: As[cc][row] = Th[b0+row][k][kc+cc]
    {
      int rb  = tid >> 3;          // 0..31
      int cc0 = (tid & 7) * 4;     // 0,4,..,28
      #pragma unroll
      for (int rr = 0; rr < 128; rr += 32) {
        float4 v = *(const float4*)&Th[((size_t)(b0 + rb + rr) * PP + k) * PP + kc + cc0];
        As[cc0 + 0][rb + rr] = v.x;
        As[cc0 + 1][rb + rr] = v.y;
        As[cc0 + 2][rb + rr] = v.z;
        As[cc0 + 3][rb + rr] = v.w;
      }
    }
    // stage B: Bs[cc][nn] = WP[k][kc+cc][n0+nn]
    {
      int nn0 = (tid & 31) * 4;    // 0..124
      int cc  = tid >> 5;          // 0..7
      #pragma unroll
      for (int c2 = 0; c2 < 32; c2 += 8) {
        int n = n0 + nn0;
        const float* src = &WP[((size_t)k * PP + kc + cc + c2) * NS + n];
        float4 v;
        if (n + 3 < NS) v = *(const float4*)src;
        else {
          v.x = (n     < NS) ? src[0] : 0.f;
          v.y = (n + 1 < NS) ? src[1] : 0.f;
          v.z = (n + 2 < NS) ? src[2] : 0.f;
          v.w = 0.f;
        }
        *(float4*)&Bs[cc + c2][nn0] = v;
      }
    }
    __syncthreads();
    #pragma unroll
    for (int kk = 0; kk < 32; ++kk) {
      float4 a0 = *(const float4*)&As[kk][ty * 8];
      float4 a1 = *(const float4*)&As[kk][ty * 8 + 4];
      float4 bx = *(const float4*)&Bs[kk][tx * 8];
      float4 by = *(const float4*)&Bs[kk][tx * 8 + 4];
      float av[8] = {a0.x, a0.y, a0.z, a0.w, a1.x, a1.y, a1.z, a1.w};
      float bv[8] = {bx.x, bx.y, bx.z, bx.w, by.x, by.y, by.z, by.w};
      #pragma unroll
      for (int i = 0; i < 8; ++i)
        #pragma unroll
        for (int j = 0; j < 8; ++j) acc[i][j] += av[i] * bv[j];
    }
    __syncthreads();
  }
  // epilogue: chunk-local P write
  #pragma unroll
  for (int i = 0; i < 8; ++i) {
    int bl = blockIdx.y * 128 + ty * 8 + i;
    size_t base = ((size_t)bl * PP + k) * NS + n0 + tx * 8;
    if (n0 + tx * 8 + 7 < NS) {
      *(float4*)&P[base]     = make_float4(acc[i][0], acc[i][1], acc[i][2], acc[i][3]);
      *(float4*)&P[base + 4] = make_float4(acc[i][4], acc[i][5], acc[i][6], acc[i][7]);
    } else {
      #pragma unroll
      for (int j = 0; j < 8; ++j)
        if (n0 + tx * 8 + j < NS) P[base + j] = acc[i][j];
    }
  }
}

// ---------------- Kernel C: segmented prefix scans over k + ReLU -------------
// 512 threads: o = tid&127 (127 active), seg s = tid>>7 owns cols [32s,32s+32).
// Two sweeps: (1) per-segment totals, (2) apply carries in a single ascending
// loop (backward suffix via total-minus-inclusive-prefix). Chain length 32.
__global__ __launch_bounds__(512) void scan_c(float* __restrict__ P,
                                              const float* __restrict__ b1) {
  __shared__ float ftot[4][128];
  __shared__ float btot[4][128];
  int bl = blockIdx.x;
  int o  = threadIdx.x & 127;
  int s  = threadIdx.x >> 7;
  float* Pb = P + (size_t)bl * PP * NS;
  float fa = 0.f, ba = 0.f;
  if (o < H) {
    for (int t = 0; t < 32; ++t) {
      int col = s * 32 + t;
      fa += Pb[col * NS + o] - Pb[col * NS + H + o];   // P1 - P2
      ba += Pb[col * NS + 2 * H + o];                  // P3
    }
    ftot[s][o] = fa;
    btot[s][o] = ba;
  }
  __syncthreads();
  if (o < H) {
    float fc = 0.f, bc = 0.f;
    for (int t = 0; t < s; ++t)     fc += ftot[t][o];
    for (int t = s + 1; t < 4; ++t) bc += btot[t][o];
    float bias = b1[o];
    float p1x = 0.f, p2i = 0.f, p3i = 0.f;             // excl P1, incl P2, incl P3
    for (int t = 0; t < 32; ++t) {
      int col = s * 32 + t;
      float v1 = Pb[col * NS + o];
      float v2 = Pb[col * NS + H + o];
      float v3 = Pb[col * NS + 2 * H + o];
      float v4 = Pb[col * NS + 3 * H + o];
      p2i += v2; p3i += v3;
      float z = bias + fc + p1x - p2i + (bc + ba - p3i) + v4;
      p1x += v1;
      Pb[col * NS + o] = fmaxf(z, 0.f);                // relu(z1) into P1 slot
    }
  }
}

// ---------------- Kernel D: t12n = A @ W2 + b2, fused output scatter --------
__global__ __launch_bounds__(256) void gemm2(const float* __restrict__ P,
                                             const float* __restrict__ W2,
                                             const float* __restrict__ b2,
                                             const float* __restrict__ Th,
                                             float* __restrict__ out, int bbase) {
  __shared__ float smem[PP * H];   // 63.5 KiB; K-phase uses first 8192 floats
  float (*Al)[128]  = (float(*)[128])smem;          // [jj][col] transposed A
  float (*W2l)[128] = (float(*)[128])(smem + 4096); // [jj][o]
  int bl = blockIdx.x;
  int b  = bbase + bl;
  int tid = threadIdx.x;
  int tn = tid & 15, tm = tid >> 4;
  const float* Ab = P + (size_t)bl * PP * NS;    // relu(z1), row stride NS
  float acc[8][8];
  #pragma unroll
  for (int i = 0; i < 8; ++i)
    #pragma unroll
    for (int j = 0; j < 8; ++j) {
      int o = tn * 8 + j;
      acc[i][j] = (o < H) ? b2[o] : 0.f;
    }
  for (int kc = 0; kc < 128; kc += 32) {
    // A transposed: Al[jj][col] = Ab[col*NS + kc+jj]; garbage at kc+jj==127 is
    // harmless (multiplied by zeroed W2l row). Memory-safe: NS > 128.
    {
      int col = tid >> 3;          // 0..31
      int jj0 = (tid & 7) * 4;
      #pragma unroll
      for (int c2 = 0; c2 < 128; c2 += 32) {
        float4 v = *(const float4*)&Ab[(size_t)(col + c2) * NS + kc + jj0];
        Al[jj0 + 0][col + c2] = v.x;
        Al[jj0 + 1][col + c2] = v.y;
        Al[jj0 + 2][col + c2] = v.z;
        Al[jj0 + 3][col + c2] = v.w;
      }
    }
    // W2l[jj][o] = W2[(kc+jj)*H + o]  (scalar: H=127 rows are 4B-aligned only)
    {
      int o  = tid & 127;
      int j0 = tid >> 7;           // 0..1
      #pragma unroll
      for (int j2 = 0; j2 < 32; j2 += 2) {
        int r = kc + j0 + j2;
        W2l[j0 + j2][o] = (r < H && o < H) ? W2[(size_t)r * H + o] : 0.f;
      }
    }
    __syncthreads();
    #pragma unroll
    for (int kk = 0; kk < 32; ++kk) {
      float4 a0 = *(const float4*)&Al[kk][tm * 8];
      float4 a1 = *(const float4*)&Al[kk][tm * 8 + 4];
      float4 bx = *(const float4*)&W2l[kk][tn * 8];
      float4 by = *(const float4*)&W2l[kk][tn * 8 + 4];
      float av[8] = {a0.x, a0.y, a0.z, a0.w, a1.x, a1.y, a1.z, a1.w};
      float bv[8] = {bx.x, bx.y, bx.z, bx.w, by.x, by.y, by.z, by.w};
      #pragma unroll
      for (int i = 0; i < 8; ++i)
        #pragma unroll
        for (int j = 0; j < 8; ++j) acc[i][j] += av[i] * bv[j];
    }
    __syncthreads();
  }
  // stage t12n into LDS: smem[col*H + o]
  #pragma unroll
  for (int i = 0; i < 8; ++i) {
    int col = tm * 8 + i;
    #pragma unroll
    for (int j = 0; j < 8; ++j) {
      int o = tn * 8 + j;
      if (o < H) smem[col * H + o] = acc[i][j];
    }
  }
  __syncthreads();
  const float* Tb = Th + (size_t)b * PP * PP;
  float* ob = out + (size_t)b * PP * PP;
  for (int it = 0; it < 64; ++it) {
    int idx = tid + 256 * it;      // covers 128*128
    int r = idx >> 7, c = idx & 127;
    float th = Tb[idx];
    float val;
    if (r == c) {
      val = th;
    } else {
      int M = r > c ? r : c, m = r > c ? c : r;
      val = 129.f * smem[M * H + m] - 128.f * th;
    }
    ob[idx] = val;
  }
}

extern "C" void kernel_launch(void* const* d_in, const int* in_sizes, int n_in,
                              void* d_out, int out_size, void* d_ws, size_t ws_size,
                              hipStream_t stream) {
  const float* Th = (const float*)d_in[0];
  const float* W1 = (const float*)d_in[1];
  const float* b1 = (const float*)d_in[2];
  const float* W2 = (const float*)d_in[3];
  const float* b2 = (const float*)d_in[4];
  // d_in[5..8] (D1,d1,D2,d2) provably do not affect the returned Theta.
  float* out = (float*)d_out;

  const size_t wp_elems = (size_t)PP * PP * NS;    // 33.3 MB
  const size_t per_b    = (size_t)PP * NS;
  int BC = 1024;                                   // largest chunk that fits ws
  while (BC > 256 && (wp_elems + (size_t)BC * per_b) * sizeof(float) > ws_size)
    BC >>= 1;

  float* WP = (float*)d_ws;
  float* Pb = WP + wp_elems;

  build_wp<<<dim3(128 * 128), dim3(128), 0, stream>>>(W1, WP);
  for (int bb = 0; bb < NB; bb += BC) {
    pgemm<<<dim3(4, BC / 128, 128), dim3(256), 0, stream>>>(Th, WP, Pb, bb);
    scan_c<<<dim3(BC), dim3(512), 0, stream>>>(Pb, b1);
    gemm2<<<dim3(BC), dim3(256), 0, stream>>>(Pb, W2, b2, Th, out, bb);
  }
}

// Round 4
// 549.462 us; speedup vs baseline: 1.9310x; 1.5682x over previous
//
#include <hip/hip_runtime.h>

// Problem constants (reference: B=1024, P=128, KPASS=1)
#define PP 128        // P
#define H  127        // P-1 (hidden / MLP output dim)
#define NV 384        // 3 slots {Q,R,L} padded to 128 each
#define NB 1024       // batch

// Mathematical reduction of the reference:
//   out[b,r,c] = Theta[b,r,c]                                     if r==c
//              = 129*t12n[b,max(r,c),min(r,c)] - 128*Theta[b,r,c] otherwise
// t12n[b,col,:] = relu(feats(b,col)@W1 + b1) @ W2 + b2, feats from ORIGINAL
// Theta. Layer-1 via quadrant prefix decomposition, refactored to 3 vectors:
//   Q = P1-P2, R = P3, L = P4-P2  (per (b,k,o), dot of Th[b,k,:] with WQ/WR/WL)
//   z1[col] = b1 + prefexcl_k(Q)[col] + sufexcl_k(R)[col] + L[col]
// (identical algebra to the R0-verified 4-vector form.)

// ---------------- Kernel A: build combined masked weights -------------------
__global__ __launch_bounds__(128) void build_wp(const float* __restrict__ W1,
                                                float* __restrict__ WP) {
  int bid = blockIdx.x;            // 16384 = 128k * 128c
  int k = bid >> 7, c = bid & 127;
  int o = threadIdx.x;             // 0..127 (o==127 is zero padding)
  float v1 = 0.f, v2 = 0.f, v3 = 0.f, v4 = 0.f;
  if (o < H) {
    if (k <= 126) {                // P1 (P1[127]=0)
      if (c < k)       v1 = W1[(k*H + c)*H + o]     + W1[(c*H + k)*H + o];
      else if (c == k) v1 = W1[(k*H + k)*H + o];
      else             v1 = W1[(k*H + (c-1))*H + o] + W1[((c-1)*H + k)*H + o];
    }
    if (k >= 1 && c < k)           // P2 (P2[0]=0)
      v2 = W1[(c*H + (k-1))*H + o] + W1[((k-1)*H + c)*H + o];
    if (k >= 1) {                  // P3 (P3[0]=0)
      if (c > k)       v3 = W1[((k-1)*H + (c-1))*H + o] + W1[((c-1)*H + (k-1))*H + o];
      else if (c == k) v3 = W1[((k-1)*H + (k-1))*H + o];
    }
    if (c < k)       v4 = W1[(16129 + c)*H + o];     // P4
    else if (c == k) v4 = W1[16256*H + o];
    else             v4 = W1[(16129 + (c-1))*H + o];
  }
  size_t base = (size_t)(k*PP + c) * NV;
  WP[base + o]       = v1 - v2;    // Q
  WP[base + 128 + o] = v3;         // R
  WP[base + 256 + o] = v4 - v2;    // L
}

// ---------------- Kernel T: Tht[k][c][bl] = Th[bbase+bl][k][c] --------------
__global__ __launch_bounds__(256) void transpose_th(const float* __restrict__ Th,
                                                    float* __restrict__ Tht,
                                                    int bbase, int BC) {
  __shared__ float tile[64][65];
  int c0 = blockIdx.x * 64, b0 = blockIdx.y * 64, k = blockIdx.z;
  int tid = threadIdx.x;
  int c4 = (tid & 15) * 4, r = tid >> 4;           // r 0..15
  for (int rr = 0; rr < 64; rr += 16) {
    float4 v = *(const float4*)&Th[((size_t)(bbase + b0 + r + rr) * PP + k) * PP + c0 + c4];
    tile[r + rr][c4 + 0] = v.x; tile[r + rr][c4 + 1] = v.y;
    tile[r + rr][c4 + 2] = v.z; tile[r + rr][c4 + 3] = v.w;
  }
  __syncthreads();
  int b4 = (tid & 15) * 4, cq = tid >> 4;
  for (int cc = 0; cc < 64; cc += 16) {
    int c = cq + cc;
    float4 v = make_float4(tile[b4 + 0][c], tile[b4 + 1][c],
                           tile[b4 + 2][c], tile[b4 + 3][c]);
    *(float4*)&Tht[((size_t)k * PP + c0 + c) * BC + b0 + b4] = v;
  }
}

// ---------------- Kernel B: P[bl][k][slot*128+o] = Th[b,k,:]·W*[k,:,o] ------
// grid(3 slots, BC/128, 128 k); all staging linear float4 (zero conflicts);
// frag reads half-split (16B stride -> 2 lanes/bank, free).
__global__ __launch_bounds__(256, 4) void pgemm(const float* __restrict__ Tht,
                                                const float* __restrict__ WP,
                                                float* __restrict__ P, int BC) {
  __shared__ float As[32 * 128];   // [cc][row_b]
  __shared__ float Bs[32 * 128];   // [cc][o]
  int nt = blockIdx.x, bt = blockIdx.y, k = blockIdx.z;
  int n0 = nt * 128;
  int tid = threadIdx.x;
  int tx = tid & 15, ty = tid >> 4;                // 16 x 16
  float acc[8][8] = {};
  for (int kc = 0; kc < 128; kc += 32) {
    {
      int p4 = (tid & 31) * 4, cc = tid >> 5;      // cc 0..7
      #pragma unroll
      for (int c2 = 0; c2 < 32; c2 += 8) {
        *(float4*)&As[(cc + c2) * 128 + p4] =
            *(const float4*)&Tht[((size_t)k * PP + kc + cc + c2) * BC + bt * 128 + p4];
        *(float4*)&Bs[(cc + c2) * 128 + p4] =
            *(const float4*)&WP[(size_t)(k * PP + kc + cc + c2) * NV + n0 + p4];
      }
    }
    __syncthreads();
    #pragma unroll
    for (int kk = 0; kk < 32; ++kk) {
      float4 a0 = *(const float4*)&As[kk * 128 + ty * 4];
      float4 a1 = *(const float4*)&As[kk * 128 + 64 + ty * 4];
      float4 b0 = *(const float4*)&Bs[kk * 128 + tx * 4];
      float4 b1 = *(const float4*)&Bs[kk * 128 + 64 + tx * 4];
      float av[8] = {a0.x, a0.y, a0.z, a0.w, a1.x, a1.y, a1.z, a1.w};
      float bv[8] = {b0.x, b0.y, b0.z, b0.w, b1.x, b1.y, b1.z, b1.w};
      #pragma unroll
      for (int i = 0; i < 8; ++i)
        #pragma unroll
        for (int j = 0; j < 8; ++j) acc[i][j] = fmaf(av[i], bv[j], acc[i][j]);
    }
    __syncthreads();
  }
  #pragma unroll
  for (int i = 0; i < 8; ++i) {
    int row = (i < 4) ? ty * 4 + i : 64 + ty * 4 + (i - 4);
    size_t base = ((size_t)(bt * 128 + row) * PP + k) * NV + n0;
    *(float4*)&P[base + tx * 4]      = make_float4(acc[i][0], acc[i][1], acc[i][2], acc[i][3]);
    *(float4*)&P[base + 64 + tx * 4] = make_float4(acc[i][4], acc[i][5], acc[i][6], acc[i][7]);
  }
}

// ---------------- Kernel C: register-resident scan + ReLU -> At[bl][j][col] -
// 512 thr: s=tid>>7 owns cols [32s,32s+32), o=tid&127. Single HBM pass.
// Output written K-major (At[j][col]) so gemm2 needs no transpose staging.
__global__ __launch_bounds__(512, 4) void scan_c(const float* __restrict__ P,
                                                 float* __restrict__ At,
                                                 const float* __restrict__ b1) {
  __shared__ float zl[128 * 127];  // [col][o<127], stride 127 (+o bank-spread)
  float* ftot = zl;                // [s*128+o], dead before zl writes
  float* btot = zl + 512;
  int bl = blockIdx.x;
  int o = threadIdx.x & 127, s = threadIdx.x >> 7;
  const float* Pb = P + (size_t)bl * PP * NV;
  float q[32], r[32];
  float fa = 0.f, ba = 0.f;
  #pragma unroll
  for (int t = 0; t < 32; ++t) {
    int col = s * 32 + t;
    q[t] = Pb[col * NV + o];
    r[t] = Pb[col * NV + 128 + o];
    fa += q[t]; ba += r[t];
  }
  ftot[s * 128 + o] = fa;
  btot[s * 128 + o] = ba;
  __syncthreads();
  float fc = 0.f, bc = 0.f;
  for (int t = 0; t < s; ++t)     fc += ftot[t * 128 + o];
  for (int t = s + 1; t < 4; ++t) bc += btot[t * 128 + o];
  float b1v = (o < H) ? b1[o] : 0.f;
  __syncthreads();                 // carries read before zl overwrites ftot/btot
  float qp = 0.f, rinc = 0.f;
  #pragma unroll
  for (int t = 0; t < 32; ++t) {
    int col = s * 32 + t;
    float L = Pb[col * NV + 256 + o];
    rinc += r[t];                                  // inclusive R
    float z = b1v + fc + qp + bc + (ba - rinc) + L;
    qp += q[t];                                    // exclusive Q
    if (o < H) zl[col * 127 + o] = fmaxf(z, 0.f);
  }
  __syncthreads();
  float* Ab = At + (size_t)bl * PP * PP;
  for (int idx = threadIdx.x; idx < PP * PP; idx += 512) {
    int oo = idx >> 7, col = idx & 127;
    Ab[idx] = (oo < H) ? zl[col * 127 + oo] : 0.f; // At[oo][col], coalesced
  }
}

// ---------------- Kernel D: t12n = A@W2 + b2, fused scatter epilogue --------
__global__ __launch_bounds__(256, 4) void gemm2(const float* __restrict__ At,
                                                const float* __restrict__ W2,
                                                const float* __restrict__ b2,
                                                const float* __restrict__ Th,
                                                float* __restrict__ out, int bbase) {
  __shared__ float smem[PP * H];   // 63.5 KiB; K-phase aliases first 32KB
  float* Al  = smem;               // [jj][col]  (K-major, direct copy from At)
  float* W2l = smem + 4096;        // [jj][o]
  int bl = blockIdx.x, b = bbase + bl;
  int tid = threadIdx.x;
  int tn = tid & 15, tm = tid >> 4;
  const float* Ab = At + (size_t)bl * PP * PP;
  float acc[8][8];
  #pragma unroll
  for (int i = 0; i < 8; ++i)
    #pragma unroll
    for (int j = 0; j < 8; ++j) {
      int oc = (j < 4) ? tn * 4 + j : 64 + tn * 4 + (j - 4);
      acc[i][j] = (oc < H) ? b2[oc] : 0.f;
    }
  for (int kc = 0; kc < 128; kc += 32) {
    {
      int c4 = (tid & 31) * 4, jj = tid >> 5;
      #pragma unroll
      for (int j2 = 0; j2 < 32; j2 += 8)
        *(float4*)&Al[(jj + j2) * 128 + c4] =
            *(const float4*)&Ab[(size_t)(kc + jj + j2) * 128 + c4];
      int oo = tid & 127, j0 = tid >> 7;           // 0..1
      #pragma unroll
      for (int j2 = 0; j2 < 32; j2 += 2) {
        int row = kc + j0 + j2;
        W2l[(j0 + j2) * 128 + oo] = (row < H && oo < H) ? W2[(size_t)row * H + oo] : 0.f;
      }
    }
    __syncthreads();
    #pragma unroll
    for (int kk = 0; kk < 32; ++kk) {
      float4 a0 = *(const float4*)&Al[kk * 128 + tm * 4];
      float4 a1 = *(const float4*)&Al[kk * 128 + 64 + tm * 4];
      float4 b0 = *(const float4*)&W2l[kk * 128 + tn * 4];
      float4 b1 = *(const float4*)&W2l[kk * 128 + 64 + tn * 4];
      float av[8] = {a0.x, a0.y, a0.z, a0.w, a1.x, a1.y, a1.z, a1.w};
      float bv[8] = {b0.x, b0.y, b0.z, b0.w, b1.x, b1.y, b1.z, b1.w};
      #pragma unroll
      for (int i = 0; i < 8; ++i)
        #pragma unroll
        for (int j = 0; j < 8; ++j) acc[i][j] = fmaf(av[i], bv[j], acc[i][j]);
    }
    __syncthreads();
  }
  #pragma unroll
  for (int i = 0; i < 8; ++i) {
    int row = (i < 4) ? tm * 4 + i : 64 + tm * 4 + (i - 4);
    #pragma unroll
    for (int j = 0; j < 8; ++j) {
      int oc = (j < 4) ? tn * 4 + j : 64 + tn * 4 + (j - 4);
      if (oc < H) smem[row * H + oc] = acc[i][j];  // t12n[b][row][oc]
    }
  }
  __syncthreads();
  const float* Tb = Th + (size_t)b * PP * PP;
  float* ob = out + (size_t)b * PP * PP;
  for (int it = 0; it < 64; ++it) {
    int idx = tid + 256 * it;      // covers 128*128
    int rr = idx >> 7, cc = idx & 127;
    float th = Tb[idx];
    float val;
    if (rr == cc) val = th;
    else {
      int M = rr > cc ? rr : cc, m = rr > cc ? cc : rr;
      val = 129.f * smem[M * H + m] - 128.f * th;
    }
    ob[idx] = val;
  }
}

extern "C" void kernel_launch(void* const* d_in, const int* in_sizes, int n_in,
                              void* d_out, int out_size, void* d_ws, size_t ws_size,
                              hipStream_t stream) {
  const float* Th = (const float*)d_in[0];
  const float* W1 = (const float*)d_in[1];
  const float* b1 = (const float*)d_in[2];
  const float* W2 = (const float*)d_in[3];
  const float* b2 = (const float*)d_in[4];
  // d_in[5..8] (D1,d1,D2,d2) provably do not affect the returned Theta.
  float* out = (float*)d_out;

  const size_t wp_elems = (size_t)PP * PP * NV;    // 6.29M floats = 25.2MB
  int BC = 1024;                                   // chunk: Tht/At + P must fit
  while (BC > 128 &&
         (wp_elems + (size_t)BC * PP * PP + (size_t)BC * PP * NV) * 4 > ws_size)
    BC >>= 1;

  float* WP  = (float*)d_ws;
  float* Tht = WP + wp_elems;                      // BC*16384 f; reused as At
  float* Pb  = Tht + (size_t)BC * PP * PP;         // BC*PP*NV f

  build_wp<<<dim3(16384), dim3(128), 0, stream>>>(W1, WP);
  for (int bb = 0; bb < NB; bb += BC) {
    transpose_th<<<dim3(2, BC / 64, 128), dim3(256), 0, stream>>>(Th, Tht, bb, BC);
    pgemm<<<dim3(3, BC / 128, 128), dim3(256), 0, stream>>>(Tht, WP, Pb, BC);
    scan_c<<<dim3(BC), dim3(512), 0, stream>>>(Pb, Tht, b1);   // At overlays Tht
    gemm2<<<dim3(BC), dim3(256), 0, stream>>>(Tht, W2, b2, Th, out, bb);
  }
}